// Round 1
// baseline (269.395 us; speedup 1.0000x reference)
//
#include <hip/hip_runtime.h>
#include <hip/hip_bf16.h>

#define SL  2048
#define BSZ 32
#define DIM 1024
#define NH  16
#define HD  64

typedef __attribute__((ext_vector_type(4))) float f32x4;
typedef __attribute__((ext_vector_type(8))) short s16x8;

static __device__ __forceinline__ short f2bf(float f) {
    union { float f; unsigned u; } v; v.f = f;
    unsigned r = (v.u + 0x7fffu + ((v.u >> 16) & 1u)) >> 16;  // RNE
    return (short)r;
}

// O[b][o] = dot(A_row, W[o][:]);  A_row = A + (hshift>=0 ? (b*NH + (o>>hshift)) : b)*DIM
__global__ __launch_bounds__(128) void k_smallgemm(const float* __restrict__ A,
                                                   const float* __restrict__ W,
                                                   float* __restrict__ O, int hshift) {
    int b = blockIdx.x & 31;
    int o = (blockIdx.x >> 5) * 128 + threadIdx.x;
    const float* arow = A + (size_t)((hshift >= 0) ? (b * NH + (o >> hshift)) : b) * DIM;
    const float* wrow = W + (size_t)o * DIM;
    float acc0 = 0.f, acc1 = 0.f;
    for (int j = 0; j < DIM; j += 8) {
        f32x4 a0 = *(const f32x4*)(arow + j);
        f32x4 a1 = *(const f32x4*)(arow + j + 4);
        f32x4 w0 = *(const f32x4*)(wrow + j);
        f32x4 w1 = *(const f32x4*)(wrow + j + 4);
        acc0 += a0[0]*w0[0] + a0[1]*w0[1] + a0[2]*w0[2] + a0[3]*w0[3];
        acc1 += a1[0]*w1[0] + a1[1]*w1[1] + a1[2]*w1[2] + a1[3]*w1[3];
    }
    O[(size_t)b * DIM + o] = acc0 + acc1;
}

// u[b][h][j] = (1/8) * sum_i qp[b][h*64+i] * Wk[h*64+i][j], stored bf16
__global__ __launch_bounds__(256) void k_u(const float* __restrict__ qp,
                                           const float* __restrict__ Wk,
                                           short* __restrict__ u) {
    int b = blockIdx.x & 31;
    int h = blockIdx.x >> 5;
    __shared__ float sq[HD];
    int t = threadIdx.x;
    if (t < HD) sq[t] = qp[(size_t)b * DIM + h * HD + t] * 0.125f;
    __syncthreads();
    int j = t * 4;
    f32x4 acc = {0.f, 0.f, 0.f, 0.f};
    const float* wbase = Wk + (size_t)(h * HD) * DIM + j;
#pragma unroll 4
    for (int i = 0; i < HD; ++i) {
        f32x4 wv = *(const f32x4*)(wbase + (size_t)i * DIM);
        acc += sq[i] * wv;
    }
    ushort4 o;
    o.x = (unsigned short)f2bf(acc[0]);
    o.y = (unsigned short)f2bf(acc[1]);
    o.z = (unsigned short)f2bf(acc[2]);
    o.w = (unsigned short)f2bf(acc[3]);
    *(ushort4*)(u + ((size_t)(b * NH + h)) * DIM + j) = o;
}

// dot[b][s][h] = keys[s,b,:] . u[b,h,:]   (u already has the 1/8)
// grid: 32 b x 16 s-tiles of 128; 4 waves, each wave 2 MFMA m-tiles (32 s rows)
__global__ __launch_bounds__(256) void k_dot(const float* __restrict__ keys,
                                             const short* __restrict__ u,
                                             float* __restrict__ dot) {
    int b  = blockIdx.x & 31;
    int s0 = (blockIdx.x >> 5) * 128;
    __shared__ short ulds[NH][DIM + 8];  // +8 shorts pad -> 2064B row stride (bank-spread)
    {
        const uint4* src = (const uint4*)(u + (size_t)b * NH * DIM);
        for (int idx = threadIdx.x; idx < NH * DIM / 8; idx += 256) {
            int row = idx >> 7;
            int col = (idx & 127) * 8;
            *(uint4*)&ulds[row][col] = src[idx];
        }
    }
    __syncthreads();
    int lane = threadIdx.x & 63;
    int wave = threadIdx.x >> 6;
    int lrow = lane & 15;
    int kgrp = lane >> 4;
    f32x4 acc0 = {0.f,0.f,0.f,0.f}, acc1 = {0.f,0.f,0.f,0.f};
    const float* ka = keys + ((size_t)(s0 + wave * 32 + lrow) * BSZ + b) * DIM;
    const float* kb = ka + (size_t)16 * BSZ * DIM;
#pragma unroll 2
    for (int k0 = 0; k0 < DIM; k0 += 32) {
        int kj = k0 + kgrp * 8;
        s16x8 bf = *(const s16x8*)&ulds[lrow][kj];     // B-frag: u[h=lane&15][kj..kj+7]
        f32x4 a0 = *(const f32x4*)(ka + kj);
        f32x4 a1 = *(const f32x4*)(ka + kj + 4);
        s16x8 af;
        af[0]=f2bf(a0[0]); af[1]=f2bf(a0[1]); af[2]=f2bf(a0[2]); af[3]=f2bf(a0[3]);
        af[4]=f2bf(a1[0]); af[5]=f2bf(a1[1]); af[6]=f2bf(a1[2]); af[7]=f2bf(a1[3]);
        acc0 = __builtin_amdgcn_mfma_f32_16x16x32_bf16(af, bf, acc0, 0, 0, 0);
        f32x4 c0 = *(const f32x4*)(kb + kj);
        f32x4 c1 = *(const f32x4*)(kb + kj + 4);
        s16x8 ag;
        ag[0]=f2bf(c0[0]); ag[1]=f2bf(c0[1]); ag[2]=f2bf(c0[2]); ag[3]=f2bf(c0[3]);
        ag[4]=f2bf(c1[0]); ag[5]=f2bf(c1[1]); ag[6]=f2bf(c1[2]); ag[7]=f2bf(c1[3]);
        acc1 = __builtin_amdgcn_mfma_f32_16x16x32_bf16(ag, bf, acc1, 0, 0, 0);
    }
    // C/D layout (m89): col(h)=lane&15, row=(lane>>4)*4+reg
    size_t obase = ((size_t)b * SL + (s0 + wave * 32 + kgrp * 4)) * NH + lrow;
#pragma unroll
    for (int r = 0; r < 4; ++r) {
        dot[obase + (size_t)r * NH]        = acc0[r];
        dot[obase + (size_t)(16 + r) * NH] = acc1[r];
    }
}

// per (b,h): M = max_s dot, T = M + log(sum exp(dot - M)); then dot <- dot - T  (log_softmax)
__global__ __launch_bounds__(256) void k_lsm(float* __restrict__ dot) {
    int b = blockIdx.x;
    int t = threadIdx.x;
    int h = t & 15, grp = t >> 4;
    float* base = dot + (size_t)b * SL * NH;
    __shared__ float red[16][17];
    __shared__ float Mh[16], Th[16];
    float m = -1e30f;
    for (int s = grp; s < SL; s += 16) m = fmaxf(m, base[s * NH + h]);
    red[grp][h] = m;
    __syncthreads();
    if (t < 16) {
        float mm = red[0][t];
        for (int g = 1; g < 16; ++g) mm = fmaxf(mm, red[g][t]);
        Mh[t] = mm;
    }
    __syncthreads();
    float mm = Mh[h];
    float sum = 0.f;
    for (int s = grp; s < SL; s += 16) sum += __expf(base[s * NH + h] - mm);
    red[grp][h] = sum;
    __syncthreads();
    if (t < 16) {
        float ss = 0.f;
        for (int g = 0; g < 16; ++g) ss += red[g][t];
        Th[t] = Mh[t] + __logf(ss);
    }
    __syncthreads();
    f32x4* b4 = (f32x4*)base;
    for (int idx = t; idx < SL * NH / 4; idx += 256) {
        f32x4 v = b4[idx];
        int hh = (idx & 3) * 4;
        v[0] -= Th[hh]; v[1] -= Th[hh + 1]; v[2] -= Th[hh + 2]; v[3] -= Th[hh + 3];
        b4[idx] = v;
    }
}

// z[b][h][j] = sum_s w[b][s][h] * values[s][b][j]
// grid: 32 b x 16 j-chunks (64 j each). thread = (ssub=t>>4, jq=t&15) -> 4 j, 16 h accs
__global__ __launch_bounds__(256) void k_z(const float* __restrict__ values,
                                           const float* __restrict__ w,
                                           float* __restrict__ z) {
    int b  = blockIdx.x & 31;
    int jc = blockIdx.x >> 5;
    int t = threadIdx.x;
    int ssub = t >> 4;
    int jq = t & 15;
    int j = jc * 64 + jq * 4;
    f32x4 acc[NH];
#pragma unroll
    for (int h = 0; h < NH; ++h) acc[h] = (f32x4){0.f,0.f,0.f,0.f};
    const float* vbase = values + (size_t)b * DIM + j;
    const float* wbase = w + (size_t)b * SL * NH;
#pragma unroll 4
    for (int s = ssub; s < SL; s += 16) {
        f32x4 v = *(const f32x4*)(vbase + (size_t)s * (BSZ * DIM));
        const f32x4* wr = (const f32x4*)(wbase + s * NH);
        float ws[16];
        *(f32x4*)(ws + 0)  = wr[0];
        *(f32x4*)(ws + 4)  = wr[1];
        *(f32x4*)(ws + 8)  = wr[2];
        *(f32x4*)(ws + 12) = wr[3];
#pragma unroll
        for (int h = 0; h < NH; ++h) acc[h] += v * ws[h];
    }
    __shared__ f32x4 lds[16 * 16 * 16];  // [ssub][h][jq], 64 KB
#pragma unroll
    for (int h = 0; h < NH; ++h) lds[(ssub * 16 + h) * 16 + jq] = acc[h];
    __syncthreads();
    int h2 = t >> 4, q = t & 15;
    f32x4 sum = (f32x4){0.f,0.f,0.f,0.f};
#pragma unroll
    for (int sub = 0; sub < 16; ++sub) sum += lds[(sub * 16 + h2) * 16 + q];
    *(f32x4*)(z + ((size_t)(b * NH + h2)) * DIM + jc * 64 + q * 4) = sum;
}

extern "C" void kernel_launch(void* const* d_in, const int* in_sizes, int n_in,
                              void* d_out, int out_size, void* d_ws, size_t ws_size,
                              hipStream_t stream) {
    const float* query  = (const float*)d_in[0];
    const float* keys   = (const float*)d_in[1];
    const float* values = (const float*)d_in[2];
    const float* Wq = (const float*)d_in[3];
    const float* Wk = (const float*)d_in[4];
    const float* Wv = (const float*)d_in[5];
    const float* Wo = (const float*)d_in[6];
    float* out = (float*)d_out;

    char* ws = (char*)d_ws;
    float* qp   = (float*)(ws + 0);                                  // 128 KB
    short* u    = (short*)(ws + 131072);                             // 1 MB  (bf16 bits)
    float* dotb = (float*)(ws + 131072 + 1048576);                   // 4 MB  [b][s][h]
    float* z    = (float*)(ws + 131072 + 1048576 + 4194304);         // 2 MB  [b][h][j]
    float* attn = (float*)(ws + 131072 + 1048576 + 4194304 + 2097152); // 128 KB

    hipLaunchKernelGGL(k_smallgemm, dim3(256), dim3(128), 0, stream, query, Wq, qp, -1);
    hipLaunchKernelGGL(k_u,         dim3(512), dim3(256), 0, stream, qp, Wk, u);
    hipLaunchKernelGGL(k_dot,       dim3(512), dim3(256), 0, stream, keys, u, dotb);
    hipLaunchKernelGGL(k_lsm,       dim3(32),  dim3(256), 0, stream, dotb);
    hipLaunchKernelGGL(k_z,         dim3(512), dim3(256), 0, stream, values, dotb, z);
    hipLaunchKernelGGL(k_smallgemm, dim3(256), dim3(128), 0, stream, z, Wv, attn, 6);
    hipLaunchKernelGGL(k_smallgemm, dim3(256), dim3(128), 0, stream, attn, Wo, out, -1);
}

// Round 2
// 241.935 us; speedup vs baseline: 1.1135x; 1.1135x over previous
//
#include <hip/hip_runtime.h>

#define SL  2048
#define BSZ 32
#define DIM 1024
#define NH  16
#define HD  64

typedef __attribute__((ext_vector_type(4))) float f32x4;
typedef __attribute__((ext_vector_type(8))) short s16x8;

static __device__ __forceinline__ short f2bf(float f) {
    union { float f; unsigned u; } v; v.f = f;
    unsigned r = (v.u + 0x7fffu + ((v.u >> 16) & 1u)) >> 16;  // RNE
    return (short)r;
}

// O[b][o] = dot(A_row(b,o), W[o][:])   A_row = A + (b*rmul + (hsel?oc:0))*DIM
// grid 256 = 16 oc (64 o each) x 16 bg (2 b each); block 128 = 2 waves (b) x 64 lanes (o)
// A reads are wave-uniform -> scalar loads (readfirstlane); W rows streamed per-lane.
__global__ __launch_bounds__(128) void k_gemm32(const float* __restrict__ A,
                                                const float* __restrict__ W,
                                                float* __restrict__ O,
                                                int rmul, int hsel) {
    int oc = blockIdx.x & 15;
    int bg = blockIdx.x >> 4;
    int wv = __builtin_amdgcn_readfirstlane(threadIdx.x >> 6);
    int lane = threadIdx.x & 63;
    int b = bg * 2 + wv;
    int o = oc * 64 + lane;
    int row = b * rmul + (hsel ? oc : 0);
    const float* arow = A + (size_t)row * DIM;
    const float* wrow = W + (size_t)o * DIM;
    f32x4 acc = {0.f, 0.f, 0.f, 0.f};
#pragma unroll 4
    for (int k = 0; k < DIM; k += 4) {
        f32x4 a = *(const f32x4*)(arow + k);   // uniform -> s_load
        f32x4 w = *(const f32x4*)(wrow + k);
        acc += a * w;
    }
    O[(size_t)b * DIM + o] = acc[0] + acc[1] + acc[2] + acc[3];
}

// u[b][h][j] = 0.125 * sum_i qp[b][h*64+i] * Wk[h*64+i][j], bf16 out.
// grid 2048 = 16 jc x 16 h x 8 bg; block 256 = 4 waves (b) x 64 lanes (j).
// Wk rows read contiguously across lanes; qp reads wave-uniform scalar.
__global__ __launch_bounds__(256) void k_ut(const float* __restrict__ qp,
                                            const float* __restrict__ Wk,
                                            short* __restrict__ u) {
    int idx = blockIdx.x;
    int jc = idx & 15;
    int h  = (idx >> 4) & 15;
    int bg = idx >> 8;
    int wv = __builtin_amdgcn_readfirstlane(threadIdx.x >> 6);
    int lane = threadIdx.x & 63;
    int b = bg * 4 + wv;
    int j = jc * 64 + lane;
    const float* qrow = qp + (size_t)b * DIM + h * HD;
    const float* wcol = Wk + (size_t)(h * HD) * DIM + j;
    float acc = 0.f;
#pragma unroll 8
    for (int i = 0; i < HD; ++i) acc += qrow[i] * wcol[(size_t)i * DIM];
    u[((size_t)(b * NH + h)) * DIM + j] = f2bf(acc * 0.125f);
}

// dot[b][s][h] = keys[s,b,:] . u[b,h,:]   (u already has the 1/8)
__global__ __launch_bounds__(256) void k_dot(const float* __restrict__ keys,
                                             const short* __restrict__ u,
                                             float* __restrict__ dot) {
    int b  = blockIdx.x & 31;
    int s0 = (blockIdx.x >> 5) * 128;
    __shared__ short ulds[NH][DIM + 8];
    {
        const uint4* src = (const uint4*)(u + (size_t)b * NH * DIM);
        for (int idx = threadIdx.x; idx < NH * DIM / 8; idx += 256) {
            int row = idx >> 7;
            int col = (idx & 127) * 8;
            *(uint4*)&ulds[row][col] = src[idx];
        }
    }
    __syncthreads();
    int lane = threadIdx.x & 63;
    int wave = threadIdx.x >> 6;
    int lrow = lane & 15;
    int kgrp = lane >> 4;
    f32x4 acc0 = {0.f,0.f,0.f,0.f}, acc1 = {0.f,0.f,0.f,0.f};
    const float* ka = keys + ((size_t)(s0 + wave * 32 + lrow) * BSZ + b) * DIM;
    const float* kb = ka + (size_t)16 * BSZ * DIM;
#pragma unroll 2
    for (int k0 = 0; k0 < DIM; k0 += 32) {
        int kj = k0 + kgrp * 8;
        s16x8 bf = *(const s16x8*)&ulds[lrow][kj];
        f32x4 a0 = *(const f32x4*)(ka + kj);
        f32x4 a1 = *(const f32x4*)(ka + kj + 4);
        s16x8 af;
        af[0]=f2bf(a0[0]); af[1]=f2bf(a0[1]); af[2]=f2bf(a0[2]); af[3]=f2bf(a0[3]);
        af[4]=f2bf(a1[0]); af[5]=f2bf(a1[1]); af[6]=f2bf(a1[2]); af[7]=f2bf(a1[3]);
        acc0 = __builtin_amdgcn_mfma_f32_16x16x32_bf16(af, bf, acc0, 0, 0, 0);
        f32x4 c0 = *(const f32x4*)(kb + kj);
        f32x4 c1 = *(const f32x4*)(kb + kj + 4);
        s16x8 ag;
        ag[0]=f2bf(c0[0]); ag[1]=f2bf(c0[1]); ag[2]=f2bf(c0[2]); ag[3]=f2bf(c0[3]);
        ag[4]=f2bf(c1[0]); ag[5]=f2bf(c1[1]); ag[6]=f2bf(c1[2]); ag[7]=f2bf(c1[3]);
        acc1 = __builtin_amdgcn_mfma_f32_16x16x32_bf16(ag, bf, acc1, 0, 0, 0);
    }
    size_t obase = ((size_t)b * SL + (s0 + wave * 32 + kgrp * 4)) * NH + lrow;
#pragma unroll
    for (int r = 0; r < 4; ++r) {
        dot[obase + (size_t)r * NH]        = acc0[r];
        dot[obase + (size_t)(16 + r) * NH] = acc1[r];
    }
}

// T[b][h] = logsumexp_s dot[b][s][h]   (dot untouched)
__global__ __launch_bounds__(1024) void k_red(const float* __restrict__ dot,
                                              float* __restrict__ T) {
    int b = blockIdx.x, t = threadIdx.x;
    const f32x4* base = (const f32x4*)(dot + (size_t)b * SL * NH);
    __shared__ f32x4 red[1024];
    __shared__ float Mh[16];
    f32x4 m = {-1e30f, -1e30f, -1e30f, -1e30f};
#pragma unroll
    for (int k = 0; k < 8; ++k) {
        f32x4 v = base[t + k * 1024];
        m[0]=fmaxf(m[0],v[0]); m[1]=fmaxf(m[1],v[1]);
        m[2]=fmaxf(m[2],v[2]); m[3]=fmaxf(m[3],v[3]);
    }
    red[t] = m;
    __syncthreads();
    for (int s = 512; s >= 4; s >>= 1) {
        if (t < s) {
            f32x4 a = red[t], c = red[t + s];
            a[0]=fmaxf(a[0],c[0]); a[1]=fmaxf(a[1],c[1]);
            a[2]=fmaxf(a[2],c[2]); a[3]=fmaxf(a[3],c[3]);
            red[t] = a;
        }
        __syncthreads();
    }
    if (t < 4) { f32x4 mm = red[t]; for (int i = 0; i < 4; ++i) Mh[t*4+i] = mm[i]; }
    __syncthreads();
    int hq = t & 3;
    f32x4 M4;
    M4[0]=Mh[hq*4]; M4[1]=Mh[hq*4+1]; M4[2]=Mh[hq*4+2]; M4[3]=Mh[hq*4+3];
    f32x4 ssum = {0.f,0.f,0.f,0.f};
#pragma unroll
    for (int k = 0; k < 8; ++k) {
        f32x4 v = base[t + k * 1024];
        ssum[0]+=__expf(v[0]-M4[0]); ssum[1]+=__expf(v[1]-M4[1]);
        ssum[2]+=__expf(v[2]-M4[2]); ssum[3]+=__expf(v[3]-M4[3]);
    }
    __syncthreads();
    red[t] = ssum;
    __syncthreads();
    for (int s = 512; s >= 4; s >>= 1) {
        if (t < s) {
            f32x4 a = red[t], c = red[t + s];
            a += c;
            red[t] = a;
        }
        __syncthreads();
    }
    if (t < 4) {
        f32x4 ss = red[t];
        for (int i = 0; i < 4; ++i)
            T[b * NH + t * 4 + i] = Mh[t * 4 + i] + __logf(ss[i]);
    }
}

// z[b][h][j] = sum_s (dot[b][s][h]-T[b][h]) * values[s][b][j]
//            = sum_s dot*v  -  T[b][h] * sum_s v
__global__ __launch_bounds__(256) void k_z(const float* __restrict__ values,
                                           const float* __restrict__ w,
                                           const float* __restrict__ T,
                                           float* __restrict__ z) {
    int b  = blockIdx.x & 31;
    int jc = blockIdx.x >> 5;
    int t = threadIdx.x;
    int ssub = t >> 4;
    int jq = t & 15;
    int j = jc * 64 + jq * 4;
    f32x4 acc[NH];
#pragma unroll
    for (int h = 0; h < NH; ++h) acc[h] = (f32x4){0.f,0.f,0.f,0.f};
    f32x4 accV = {0.f,0.f,0.f,0.f};
    const float* vbase = values + (size_t)b * DIM + j;
    const float* wbase = w + (size_t)b * SL * NH;
#pragma unroll 4
    for (int s = ssub; s < SL; s += 16) {
        f32x4 v = *(const f32x4*)(vbase + (size_t)s * (BSZ * DIM));
        const f32x4* wr = (const f32x4*)(wbase + s * NH);
        float ws[16];
        *(f32x4*)(ws + 0)  = wr[0];
        *(f32x4*)(ws + 4)  = wr[1];
        *(f32x4*)(ws + 8)  = wr[2];
        *(f32x4*)(ws + 12) = wr[3];
#pragma unroll
        for (int h = 0; h < NH; ++h) acc[h] += v * ws[h];
        accV += v;
    }
    __shared__ f32x4 lds[16 * 16 * 16];  // 64 KB
#pragma unroll
    for (int h = 0; h < NH; ++h) lds[(ssub * 16 + h) * 16 + jq] = acc[h];
    __syncthreads();
    int h2 = t >> 4, q = t & 15;
    f32x4 sumW = {0.f,0.f,0.f,0.f};
#pragma unroll
    for (int sub = 0; sub < 16; ++sub) sumW += lds[(sub * 16 + h2) * 16 + q];
    __syncthreads();
    lds[ssub * 16 + jq] = accV;
    __syncthreads();
    f32x4 sumV = {0.f,0.f,0.f,0.f};
#pragma unroll
    for (int sub = 0; sub < 16; ++sub) sumV += lds[sub * 16 + q];
    float Th = T[b * NH + h2];
    f32x4 zv = sumW - Th * sumV;
    *(f32x4*)(z + ((size_t)(b * NH + h2)) * DIM + jc * 64 + q * 4) = zv;
}

extern "C" void kernel_launch(void* const* d_in, const int* in_sizes, int n_in,
                              void* d_out, int out_size, void* d_ws, size_t ws_size,
                              hipStream_t stream) {
    const float* query  = (const float*)d_in[0];
    const float* keys   = (const float*)d_in[1];
    const float* values = (const float*)d_in[2];
    const float* Wq = (const float*)d_in[3];
    const float* Wk = (const float*)d_in[4];
    const float* Wv = (const float*)d_in[5];
    const float* Wo = (const float*)d_in[6];
    float* out = (float*)d_out;

    char* ws = (char*)d_ws;
    float* qp   = (float*)(ws + 0);                         // 128 KB
    short* u    = (short*)(ws + (128 << 10));               // 1 MB
    float* dotb = (float*)(ws + (128 << 10) + (1 << 20));   // 4 MB  [b][s][h]
    float* z    = (float*)(ws + (128 << 10) + (5 << 20));   // 2 MB  [b][h][j]
    float* attn = (float*)(ws + (128 << 10) + (7 << 20));   // 128 KB
    float* T    = (float*)(ws + (256 << 10) + (7 << 20));   // 2 KB

    hipLaunchKernelGGL(k_gemm32, dim3(256),  dim3(128), 0, stream, query, Wq, qp, 1, 0);
    hipLaunchKernelGGL(k_ut,     dim3(2048), dim3(256), 0, stream, qp, Wk, u);
    hipLaunchKernelGGL(k_dot,    dim3(512),  dim3(256), 0, stream, keys, u, dotb);
    hipLaunchKernelGGL(k_red,    dim3(32),   dim3(1024),0, stream, dotb, T);
    hipLaunchKernelGGL(k_z,      dim3(512),  dim3(256), 0, stream, values, dotb, T, z);
    hipLaunchKernelGGL(k_gemm32, dim3(256),  dim3(128), 0, stream, z, Wv, attn, 16, 1);
    hipLaunchKernelGGL(k_gemm32, dim3(256),  dim3(128), 0, stream, attn, Wo, out, 1, 0);
}

// Round 3
// 199.143 us; speedup vs baseline: 1.3528x; 1.2149x over previous
//
#include <hip/hip_runtime.h>

#define SL  2048
#define BSZ 32
#define DIM 1024
#define NH  16
#define HD  64

typedef __attribute__((ext_vector_type(4))) float f32x4;
typedef __attribute__((ext_vector_type(8))) short s16x8;

static __device__ __forceinline__ short f2bf(float f) {
    union { float f; unsigned u; } v; v.f = f;
    unsigned r = (v.u + 0x7fffu + ((v.u >> 16) & 1u)) >> 16;  // RNE
    return (short)r;
}

// O[b][o] = dot(A_row(b,o) [+A2_row], W[o][:])
// grid 512 = 16 oc x 32 b; block 256 = 4 waves, each wave one K-quarter (256).
template<bool DUAL>
__global__ __launch_bounds__(256) void k_gemm(const float* __restrict__ A,
                                              const float* __restrict__ A2,
                                              const float* __restrict__ W,
                                              float* __restrict__ O,
                                              int rmul, int hsel) {
    int oc = blockIdx.x & 15;
    int b  = blockIdx.x >> 4;
    int wv = __builtin_amdgcn_readfirstlane(threadIdx.x >> 6);
    int lane = threadIdx.x & 63;
    int o = oc * 64 + lane;
    int row = b * rmul + (hsel ? oc : 0);
    const float* arow  = A + (size_t)row * DIM + wv * 256;
    const float* a2row = DUAL ? (A2 + (size_t)row * DIM + wv * 256) : nullptr;
    const float* wrow  = W + (size_t)o * DIM + wv * 256;
    f32x4 acc = {0.f, 0.f, 0.f, 0.f};
#pragma unroll 4
    for (int k = 0; k < 256; k += 4) {
        f32x4 a = *(const f32x4*)(arow + k);
        if (DUAL) a += *(const f32x4*)(a2row + k);
        f32x4 w = *(const f32x4*)(wrow + k);
        acc += a * w;
    }
    __shared__ float red[4][64];
    red[wv][lane] = acc[0] + acc[1] + acc[2] + acc[3];
    __syncthreads();
    int t = threadIdx.x;
    if (t < 64)
        O[(size_t)b * DIM + oc * 64 + t] = red[0][t] + red[1][t] + red[2][t] + red[3][t];
}

// u[b][h][j] = 0.125 * sum_i qp[b][h*64+i] * Wk[h*64+i][j], bf16 out.
__global__ __launch_bounds__(256) void k_ut(const float* __restrict__ qp,
                                            const float* __restrict__ Wk,
                                            short* __restrict__ u) {
    int idx = blockIdx.x;
    int jc = idx & 15;
    int h  = (idx >> 4) & 15;
    int bg = idx >> 8;
    int wv = __builtin_amdgcn_readfirstlane(threadIdx.x >> 6);
    int lane = threadIdx.x & 63;
    int b = bg * 4 + wv;
    int j = jc * 64 + lane;
    const float* qrow = qp + (size_t)b * DIM + h * HD;
    const float* wcol = Wk + (size_t)(h * HD) * DIM + j;
    float acc = 0.f;
#pragma unroll 8
    for (int i = 0; i < HD; ++i) acc += qrow[i] * wcol[(size_t)i * DIM];
    u[((size_t)(b * NH + h)) * DIM + j] = f2bf(acc * 0.125f);
}

// dot[b][s][h] = keys[s,b,:] . u[b,h,:]
// grid 1024 = 32 b x 32 s-tiles(64); block 256 = 4 waves x 16 rows.
__global__ __launch_bounds__(256, 4) void k_dot(const float* __restrict__ keys,
                                                const short* __restrict__ u,
                                                float* __restrict__ dot) {
    int b  = blockIdx.x & 31;
    int s0 = (blockIdx.x >> 5) * 64;
    __shared__ short ulds[NH][DIM + 8];
    {
        const uint4* src = (const uint4*)(u + (size_t)b * NH * DIM);
        for (int idx = threadIdx.x; idx < NH * DIM / 8; idx += 256) {
            int row = idx >> 7;
            int col = (idx & 127) * 8;
            *(uint4*)&ulds[row][col] = src[idx];
        }
    }
    __syncthreads();
    int lane = threadIdx.x & 63;
    int wave = threadIdx.x >> 6;
    int lrow = lane & 15;
    int kgrp = lane >> 4;
    f32x4 acc = {0.f, 0.f, 0.f, 0.f};
    const float* ka = keys + ((size_t)(s0 + wave * 16 + lrow) * BSZ + b) * DIM;
#pragma unroll 4
    for (int k0 = 0; k0 < DIM; k0 += 32) {
        int kj = k0 + kgrp * 8;
        s16x8 bf = *(const s16x8*)&ulds[lrow][kj];
        f32x4 a0 = *(const f32x4*)(ka + kj);
        f32x4 a1 = *(const f32x4*)(ka + kj + 4);
        s16x8 af;
        af[0]=f2bf(a0[0]); af[1]=f2bf(a0[1]); af[2]=f2bf(a0[2]); af[3]=f2bf(a0[3]);
        af[4]=f2bf(a1[0]); af[5]=f2bf(a1[1]); af[6]=f2bf(a1[2]); af[7]=f2bf(a1[3]);
        acc = __builtin_amdgcn_mfma_f32_16x16x32_bf16(af, bf, acc, 0, 0, 0);
    }
    size_t obase = ((size_t)b * SL + (s0 + wave * 16 + kgrp * 4)) * NH + lrow;
#pragma unroll
    for (int r = 0; r < 4; ++r)
        dot[obase + (size_t)r * NH] = acc[r];
}

// T[b][h] = logsumexp_s dot[b][s][h]
__global__ __launch_bounds__(1024) void k_red(const float* __restrict__ dot,
                                              float* __restrict__ T) {
    int b = blockIdx.x, t = threadIdx.x;
    const f32x4* base = (const f32x4*)(dot + (size_t)b * SL * NH);
    __shared__ f32x4 red[1024];
    __shared__ float Mh[16];
    f32x4 m = {-1e30f, -1e30f, -1e30f, -1e30f};
#pragma unroll
    for (int k = 0; k < 8; ++k) {
        f32x4 v = base[t + k * 1024];
        m[0]=fmaxf(m[0],v[0]); m[1]=fmaxf(m[1],v[1]);
        m[2]=fmaxf(m[2],v[2]); m[3]=fmaxf(m[3],v[3]);
    }
    red[t] = m;
    __syncthreads();
    for (int s = 512; s >= 4; s >>= 1) {
        if (t < s) {
            f32x4 a = red[t], c = red[t + s];
            a[0]=fmaxf(a[0],c[0]); a[1]=fmaxf(a[1],c[1]);
            a[2]=fmaxf(a[2],c[2]); a[3]=fmaxf(a[3],c[3]);
            red[t] = a;
        }
        __syncthreads();
    }
    if (t < 4) { f32x4 mm = red[t]; for (int i = 0; i < 4; ++i) Mh[t*4+i] = mm[i]; }
    __syncthreads();
    int hq = t & 3;
    f32x4 M4;
    M4[0]=Mh[hq*4]; M4[1]=Mh[hq*4+1]; M4[2]=Mh[hq*4+2]; M4[3]=Mh[hq*4+3];
    f32x4 ssum = {0.f,0.f,0.f,0.f};
#pragma unroll
    for (int k = 0; k < 8; ++k) {
        f32x4 v = base[t + k * 1024];
        ssum[0]+=__expf(v[0]-M4[0]); ssum[1]+=__expf(v[1]-M4[1]);
        ssum[2]+=__expf(v[2]-M4[2]); ssum[3]+=__expf(v[3]-M4[3]);
    }
    __syncthreads();
    red[t] = ssum;
    __syncthreads();
    for (int s = 512; s >= 4; s >>= 1) {
        if (t < s) { f32x4 a = red[t]; a += red[t + s]; red[t] = a; }
        __syncthreads();
    }
    if (t < 4) {
        f32x4 ss = red[t];
        for (int i = 0; i < 4; ++i)
            T[b * NH + t * 4 + i] = Mh[t * 4 + i] + __logf(ss[i]);
    }
}

// zp[sh][b][h][j] = sum_{s in half} dot[b][s][h]*values[s][b][j] - T[b][h]*sum_{s in half} values[s][b][j]
// grid 1024 = 32 b x 16 jc x 2 sh; block 256 = 16 ssub x 16 jq (4 j each).
// dot tile staged in LDS per 128-s phase -> vm queue carries ONLY the values stream.
__global__ __launch_bounds__(256, 4) void k_z(const float* __restrict__ values,
                                              const float* __restrict__ w,
                                              const float* __restrict__ T,
                                              float* __restrict__ z) {
    int x  = blockIdx.x;
    int b  = x & 31;
    int jc = (x >> 5) & 15;
    int sh = x >> 9;
    int t  = threadIdx.x;
    int ssub = t >> 4;
    int jq = t & 15;
    int j = jc * 64 + jq * 4;
    int wv = __builtin_amdgcn_readfirstlane(t >> 6);
    int lane = t & 63;

    __shared__ float wlds[128 * 16];        // 8 KB: dot[s0..s0+128][0..16]
    __shared__ f32x4 redW[4][16][16];       // 16 KB
    __shared__ f32x4 redV[4][16];           // 1 KB

    f32x4 acc[NH];
#pragma unroll
    for (int h = 0; h < NH; ++h) acc[h] = (f32x4){0.f,0.f,0.f,0.f};
    f32x4 accV = {0.f,0.f,0.f,0.f};

    const float* vbase = values + (size_t)b * DIM + j;
    const float* wbase = w + ((size_t)b * SL + sh * 1024) * NH;

    for (int ph = 0; ph < 8; ++ph) {
        if (ph) __syncthreads();
        // stage 8 KB contiguous dot tile: [128 s][16 h]
        {
            const f32x4* src = (const f32x4*)(wbase + ph * 128 * NH);
            f32x4* dst = (f32x4*)wlds;
            dst[t]       = src[t];
            dst[t + 256] = src[t + 256];
        }
        __syncthreads();
        int sbase = sh * 1024 + ph * 128;
#pragma unroll 4
        for (int it = 0; it < 8; ++it) {
            int s_loc = it * 16 + ssub;
            f32x4 v = *(const f32x4*)(vbase + (size_t)(sbase + s_loc) * (BSZ * DIM));
            const float* wr = wlds + s_loc * 16;
#pragma unroll
            for (int h = 0; h < NH; ++h) {
                float wh = wr[h];
                acc[h] += v * wh;
            }
            accV += v;
        }
    }

    // intra-wave reduce across ssub (lanes 16,32 apart)
#pragma unroll
    for (int h = 0; h < NH; ++h) {
#pragma unroll
        for (int e = 0; e < 4; ++e) {
            float x0 = acc[h][e];
            x0 += __shfl_xor(x0, 16);
            x0 += __shfl_xor(x0, 32);
            acc[h][e] = x0;
        }
    }
#pragma unroll
    for (int e = 0; e < 4; ++e) {
        float x0 = accV[e];
        x0 += __shfl_xor(x0, 16);
        x0 += __shfl_xor(x0, 32);
        accV[e] = x0;
    }
    if (lane < 16) {
#pragma unroll
        for (int h = 0; h < NH; ++h) redW[wv][h][lane] = acc[h];
        redV[wv][lane] = accV;
    }
    __syncthreads();
    int h2 = t >> 4, q = t & 15;
    f32x4 sumW = redW[0][h2][q] + redW[1][h2][q] + redW[2][h2][q] + redW[3][h2][q];
    f32x4 sumV = redV[0][q] + redV[1][q] + redV[2][q] + redV[3][q];
    float Th = T[b * NH + h2];
    f32x4 zv = sumW - Th * sumV;
    float* zp = z + (size_t)sh * (BSZ * NH * DIM);
    *(f32x4*)(zp + ((size_t)(b * NH + h2)) * DIM + jc * 64 + q * 4) = zv;
}

extern "C" void kernel_launch(void* const* d_in, const int* in_sizes, int n_in,
                              void* d_out, int out_size, void* d_ws, size_t ws_size,
                              hipStream_t stream) {
    const float* query  = (const float*)d_in[0];
    const float* keys   = (const float*)d_in[1];
    const float* values = (const float*)d_in[2];
    const float* Wq = (const float*)d_in[3];
    const float* Wk = (const float*)d_in[4];
    const float* Wv = (const float*)d_in[5];
    const float* Wo = (const float*)d_in[6];
    float* out = (float*)d_out;

    char* ws = (char*)d_ws;
    float* qp   = (float*)(ws + 0);                         // 128 KB
    short* u    = (short*)(ws + (128 << 10));               // 1 MB
    float* dotb = (float*)(ws + (128 << 10) + (1 << 20));   // 4 MB  [b][s][h]
    float* z0   = (float*)(ws + (128 << 10) + (5 << 20));   // 2 MB  [b][h][j]
    float* z1   = (float*)(ws + (128 << 10) + (7 << 20));   // 2 MB
    float* attn = (float*)(ws + (128 << 10) + (9 << 20));   // 128 KB
    float* T    = (float*)(ws + (256 << 10) + (9 << 20));   // 2 KB

    hipLaunchKernelGGL(k_gemm<false>, dim3(512),  dim3(256), 0, stream, query, nullptr, Wq, qp, 1, 0);
    hipLaunchKernelGGL(k_ut,          dim3(2048), dim3(256), 0, stream, qp, Wk, u);
    hipLaunchKernelGGL(k_dot,         dim3(1024), dim3(256), 0, stream, keys, u, dotb);
    hipLaunchKernelGGL(k_red,         dim3(32),   dim3(1024),0, stream, dotb, T);
    hipLaunchKernelGGL(k_z,           dim3(1024), dim3(256), 0, stream, values, dotb, T, z0);
    hipLaunchKernelGGL(k_gemm<true>,  dim3(512),  dim3(256), 0, stream, z0, z1, Wv, attn, 16, 1);
    hipLaunchKernelGGL(k_gemm<false>, dim3(512),  dim3(256), 0, stream, attn, nullptr, Wo, out, 1, 0);
}